// Round 1
// baseline (723.667 us; speedup 1.0000x reference)
//
#include <hip/hip_runtime.h>

// 2-layer LSTM (HID=10), B=2048, T=1024 main steps + F future (autoregressive) steps.
// Decomposition: 10 lanes per element (1 lane per hidden unit), 6 elements per
// 64-thread wave/block -> 342 blocks. Lane (e,u) computes the 4 gate rows for its
// unit locally; only h1/h2 broadcasts (10x ds_bpermute each) cross lanes.

#define NB 2048       // batch elements
#define TMAIN 1024    // main timesteps
#define HID 10
#define EPB 6         // elements per block (one wave)
#define XS_STRIDE 1032 // padded LDS row stride in floats (breaks bank aliasing, /4 ok)

__device__ __forceinline__ float fast_sigmoid(float x) {
    // 1/(1+exp(-x)) = 1/(1+2^(-x*log2e))
    float e = __builtin_amdgcn_exp2f(x * -1.4426950408889634f);
    return __builtin_amdgcn_rcpf(1.0f + e);
}
__device__ __forceinline__ float fast_tanh(float x) {
    // tanh(x) = 1 - 2/(1+exp(2x)) = 1 - 2/(1+2^(x*2*log2e))
    float e = __builtin_amdgcn_exp2f(x * 2.8853900817779268f);
    return 1.0f - 2.0f * __builtin_amdgcn_rcpf(1.0f + e);
}

__global__ __launch_bounds__(64, 1) void lstm2_kernel(
    const float* __restrict__ x,
    const float* __restrict__ Wih1, const float* __restrict__ Whh1,
    const float* __restrict__ bih1, const float* __restrict__ bhh1,
    const float* __restrict__ Wih2, const float* __restrict__ Whh2,
    const float* __restrict__ bih2, const float* __restrict__ bhh2,
    const float* __restrict__ Wlin, const float* __restrict__ blin,
    const int* __restrict__ futp,
    float* __restrict__ out)
{
    __shared__ float xs[EPB * XS_STRIDE];

    const int lane = threadIdx.x;
    const int blk  = blockIdx.x;
    const int F    = futp[0];
    const int OUTW = TMAIN + F;

    // ---- stage x for this block's 6 elements into LDS (float4 loads) ----
    {
        const float4* xg = (const float4*)x;
        #pragma unroll 1
        for (int f = lane; f < EPB * (TMAIN / 4); f += 64) {
            int e  = f / (TMAIN / 4);
            int t4 = f % (TMAIN / 4);
            int ge = blk * EPB + e;
            float4 v = make_float4(0.f, 0.f, 0.f, 0.f);
            if (ge < NB) v = xg[(size_t)ge * (TMAIN / 4) + t4];
            float4* dst = (float4*)&xs[e * XS_STRIDE];
            dst[t4] = v;
        }
    }
    __syncthreads();

    // ---- lane mapping ----
    const int e_raw = lane / HID;          // 0..6
    const int u     = lane - e_raw * HID;  // 0..9
    const bool laneActive = (lane < EPB * HID); // lanes 60..63 idle
    const int e     = laneActive ? e_raw : 0;
    const int ge    = blk * EPB + e;
    const bool elemActive = laneActive && (ge < NB);
    const int ebase = e * HID;

    // precomputed bpermute byte addresses for h broadcast (source lanes ebase..ebase+9)
    int baddr[HID];
    #pragma unroll
    for (int j = 0; j < HID; ++j) baddr[j] = (ebase + j) * 4;

    // ---- load weights into registers (per lane: its 4 gate rows) ----
    float wih1v[4], b1v[4], b2v[4];
    float whh1v[4][HID], wih2v[4][HID], whh2v[4][HID];
    #pragma unroll
    for (int k = 0; k < 4; ++k) {
        int g = k * HID + u;
        wih1v[k] = Wih1[g];                 // W_ih1 is [40,1]
        b1v[k]   = bih1[g] + bhh1[g];
        b2v[k]   = bih2[g] + bhh2[g];
        #pragma unroll
        for (int j = 0; j < HID; ++j) {
            whh1v[k][j] = Whh1[g * HID + j];
            wih2v[k][j] = Wih2[g * HID + j];
            whh2v[k][j] = Whh2[g * HID + j];
        }
    }
    float wlinv[HID];
    #pragma unroll
    for (int j = 0; j < HID; ++j) wlinv[j] = Wlin[j];
    const float bl = blin[0];

    // ---- state ----
    float c1 = 0.f, c2 = 0.f;
    float h1b[HID], h2b[HID];
    #pragma unroll
    for (int j = 0; j < HID; ++j) { h1b[j] = 0.f; h2b[j] = 0.f; }

    auto step = [&](float xt) -> float {
        float g[4];
        // cell 1 gates (input is scalar xt)
        #pragma unroll
        for (int k = 0; k < 4; ++k) {
            float a = fmaf(xt, wih1v[k], b1v[k]);
            #pragma unroll
            for (int j = 0; j < HID; ++j) a = fmaf(h1b[j], whh1v[k][j], a);
            g[k] = a;
        }
        float is = fast_sigmoid(g[0]);
        float fs = fast_sigmoid(g[1]);
        float gt = fast_tanh(g[2]);
        float os = fast_sigmoid(g[3]);
        c1 = fmaf(fs, c1, is * gt);
        float h1u = os * fast_tanh(c1);
        // broadcast h1 across the element's 10 lanes
        #pragma unroll
        for (int j = 0; j < HID; ++j)
            h1b[j] = __int_as_float(__builtin_amdgcn_ds_bpermute(baddr[j], __float_as_int(h1u)));

        // cell 2 gates
        #pragma unroll
        for (int k = 0; k < 4; ++k) {
            float a = b2v[k];
            #pragma unroll
            for (int j = 0; j < HID; ++j) a = fmaf(h1b[j], wih2v[k][j], a);
            #pragma unroll
            for (int j = 0; j < HID; ++j) a = fmaf(h2b[j], whh2v[k][j], a);
            g[k] = a;
        }
        is = fast_sigmoid(g[0]);
        fs = fast_sigmoid(g[1]);
        gt = fast_tanh(g[2]);
        os = fast_sigmoid(g[3]);
        c2 = fmaf(fs, c2, is * gt);
        float h2u = os * fast_tanh(c2);
        #pragma unroll
        for (int j = 0; j < HID; ++j)
            h2b[j] = __int_as_float(__builtin_amdgcn_ds_bpermute(baddr[j], __float_as_int(h2u)));

        // linear head (computed redundantly on all lanes; lane u==0 stores)
        float y = bl;
        #pragma unroll
        for (int j = 0; j < HID; ++j) y = fmaf(h2b[j], wlinv[j], y);
        return y;
    };

    float yprev = 0.f;
    #pragma unroll 1
    for (int t = 0; t < TMAIN; ++t) {
        float y = step(xs[e * XS_STRIDE + t]);
        if (u == 0 && elemActive) out[(size_t)ge * OUTW + t] = y;
        yprev = y;
    }
    #pragma unroll 1
    for (int t = 0; t < F; ++t) {
        yprev = step(yprev);
        if (u == 0 && elemActive) out[(size_t)ge * OUTW + TMAIN + t] = yprev;
    }
}

extern "C" void kernel_launch(void* const* d_in, const int* in_sizes, int n_in,
                              void* d_out, int out_size, void* d_ws, size_t ws_size,
                              hipStream_t stream) {
    const float* x    = (const float*)d_in[0];
    const float* Wih1 = (const float*)d_in[1];
    const float* Whh1 = (const float*)d_in[2];
    const float* bih1 = (const float*)d_in[3];
    const float* bhh1 = (const float*)d_in[4];
    const float* Wih2 = (const float*)d_in[5];
    const float* Whh2 = (const float*)d_in[6];
    const float* bih2 = (const float*)d_in[7];
    const float* bhh2 = (const float*)d_in[8];
    const float* Wlin = (const float*)d_in[9];
    const float* blin = (const float*)d_in[10];
    const int*   futp = (const int*)d_in[11];
    float* out = (float*)d_out;

    int grid = (NB + EPB - 1) / EPB; // 342 single-wave blocks
    lstm2_kernel<<<grid, 64, 0, stream>>>(x, Wih1, Whh1, bih1, bhh1,
                                          Wih2, Whh2, bih2, bhh2,
                                          Wlin, blin, futp, out);
}

// Round 2
// 605.446 us; speedup vs baseline: 1.1953x; 1.1953x over previous
//
#include <hip/hip_runtime.h>

// 2-layer LSTM (HID=10), B=2048, T=1024 main + F=64 future steps.
// Lane (e,u): 10 lanes per element (1 per hidden unit), 6 elements per wave,
// 342 single-wave blocks. Round 2: weights PINNED in VGPRs via asm (the round-1
// kernel had VGPR=88 -> compiler re-loaded ~130 weights from L1 every step);
// x read as float4 per 4 steps with one-group-ahead prefetch; y stored as float4.

#define NB 2048
#define TMAIN 1024
#define HID 10
#define EPB 6
#define XS_STRIDE 1032  // floats; stride*4 bytes = 4128, 16B-aligned rows

#define PIN(v) asm volatile("" : "+v"(v))

__device__ __forceinline__ float fast_sigmoid(float x) {
    float e = __builtin_amdgcn_exp2f(x * -1.4426950408889634f);
    return __builtin_amdgcn_rcpf(1.0f + e);
}
__device__ __forceinline__ float fast_tanh(float x) {
    float e = __builtin_amdgcn_exp2f(x * 2.8853900817779268f);
    return 1.0f - 2.0f * __builtin_amdgcn_rcpf(1.0f + e);
}

__global__ __launch_bounds__(64, 1) void lstm2_kernel(
    const float* __restrict__ x,
    const float* __restrict__ Wih1, const float* __restrict__ Whh1,
    const float* __restrict__ bih1, const float* __restrict__ bhh1,
    const float* __restrict__ Wih2, const float* __restrict__ Whh2,
    const float* __restrict__ bih2, const float* __restrict__ bhh2,
    const float* __restrict__ Wlin, const float* __restrict__ blin,
    const int* __restrict__ futp,
    float* __restrict__ out)
{
    __shared__ float xs[EPB * XS_STRIDE];

    const int lane = threadIdx.x;
    const int blk  = blockIdx.x;
    const int F    = futp[0];
    const int OUTW = TMAIN + F;

    // ---- stage x into LDS (float4) ----
    {
        const float4* xg = (const float4*)x;
        #pragma unroll 1
        for (int f = lane; f < EPB * (TMAIN / 4); f += 64) {
            int e  = f / (TMAIN / 4);
            int t4 = f % (TMAIN / 4);
            int ge = blk * EPB + e;
            float4 v = make_float4(0.f, 0.f, 0.f, 0.f);
            if (ge < NB) v = xg[(size_t)ge * (TMAIN / 4) + t4];
            ((float4*)&xs[e * XS_STRIDE])[t4] = v;
        }
    }
    __syncthreads();

    // ---- lane mapping ----
    const int e_raw = lane / HID;
    const int u     = lane - e_raw * HID;
    const bool laneActive = (lane < EPB * HID);
    const int e     = laneActive ? e_raw : 0;
    const int ge    = blk * EPB + e;
    const bool elemActive = laneActive && (ge < NB);
    const int ebase = e * HID;

    int baddr[HID];
    #pragma unroll
    for (int j = 0; j < HID; ++j) baddr[j] = (ebase + j) * 4;

    // ---- weights into registers, PINNED so they can't be re-loaded per step ----
    float wih1v[4], b1v[4], b2v[4];
    float whh1v[4][HID], wih2v[4][HID], whh2v[4][HID];
    #pragma unroll
    for (int k = 0; k < 4; ++k) {
        int g = k * HID + u;
        wih1v[k] = Wih1[g];
        b1v[k]   = bih1[g] + bhh1[g];
        b2v[k]   = bih2[g] + bhh2[g];
        #pragma unroll
        for (int j = 0; j < HID; ++j) {
            whh1v[k][j] = Whh1[g * HID + j];
            wih2v[k][j] = Wih2[g * HID + j];
            whh2v[k][j] = Whh2[g * HID + j];
        }
    }
    float wlinv[HID];
    #pragma unroll
    for (int j = 0; j < HID; ++j) wlinv[j] = Wlin[j];
    float bl = blin[0];

    #pragma unroll
    for (int k = 0; k < 4; ++k) {
        PIN(wih1v[k]); PIN(b1v[k]); PIN(b2v[k]);
        #pragma unroll
        for (int j = 0; j < HID; ++j) {
            PIN(whh1v[k][j]); PIN(wih2v[k][j]); PIN(whh2v[k][j]);
        }
    }
    #pragma unroll
    for (int j = 0; j < HID; ++j) PIN(wlinv[j]);
    PIN(bl);

    // ---- state ----
    float c1 = 0.f, c2 = 0.f;
    float h1b[HID], h2b[HID];
    #pragma unroll
    for (int j = 0; j < HID; ++j) { h1b[j] = 0.f; h2b[j] = 0.f; }

    auto step = [&](float xt) -> float {
        float g[4];
        #pragma unroll
        for (int k = 0; k < 4; ++k) {
            float a = fmaf(xt, wih1v[k], b1v[k]);
            #pragma unroll
            for (int j = 0; j < HID; ++j) a = fmaf(h1b[j], whh1v[k][j], a);
            g[k] = a;
        }
        float is = fast_sigmoid(g[0]);
        float fs = fast_sigmoid(g[1]);
        float gt = fast_tanh(g[2]);
        float os = fast_sigmoid(g[3]);
        c1 = fmaf(fs, c1, is * gt);
        float h1u = os * fast_tanh(c1);
        #pragma unroll
        for (int j = 0; j < HID; ++j)
            h1b[j] = __int_as_float(__builtin_amdgcn_ds_bpermute(baddr[j], __float_as_int(h1u)));

        #pragma unroll
        for (int k = 0; k < 4; ++k) {
            float a = b2v[k];
            #pragma unroll
            for (int j = 0; j < HID; ++j) a = fmaf(h1b[j], wih2v[k][j], a);
            #pragma unroll
            for (int j = 0; j < HID; ++j) a = fmaf(h2b[j], whh2v[k][j], a);
            g[k] = a;
        }
        is = fast_sigmoid(g[0]);
        fs = fast_sigmoid(g[1]);
        gt = fast_tanh(g[2]);
        os = fast_sigmoid(g[3]);
        c2 = fmaf(fs, c2, is * gt);
        float h2u = os * fast_tanh(c2);
        #pragma unroll
        for (int j = 0; j < HID; ++j)
            h2b[j] = __int_as_float(__builtin_amdgcn_ds_bpermute(baddr[j], __float_as_int(h2u)));

        float y = bl;
        #pragma unroll
        for (int j = 0; j < HID; ++j) y = fmaf(h2b[j], wlinv[j], y);
        return y;
    };

    // ---- main loop: 4 steps per iteration, prefetch next x-group ----
    const float4* xrow = (const float4*)&xs[e * XS_STRIDE];
    float4* orow = (float4*)(out + (size_t)ge * OUTW);
    float4 xv = xrow[0];
    float yprev = 0.f;
    #pragma unroll 1
    for (int t4 = 0; t4 < TMAIN / 4; ++t4) {
        float4 xn = (t4 + 1 < TMAIN / 4) ? xrow[t4 + 1] : make_float4(0.f,0.f,0.f,0.f);
        float4 yv;
        yv.x = step(xv.x);
        yv.y = step(xv.y);
        yv.z = step(xv.z);
        yv.w = step(xv.w);
        if (u == 0 && elemActive) orow[t4] = yv;
        yprev = yv.w;
        xv = xn;
    }

    // ---- future loop: groups of 4 + scalar tail ----
    int t = 0;
    #pragma unroll 1
    for (; t + 3 < F; t += 4) {
        float4 yv;
        yv.x = step(yprev);
        yv.y = step(yv.x);
        yv.z = step(yv.y);
        yv.w = step(yv.z);
        if (u == 0 && elemActive) orow[(TMAIN + t) / 4] = yv;
        yprev = yv.w;
    }
    #pragma unroll 1
    for (; t < F; ++t) {
        yprev = step(yprev);
        if (u == 0 && elemActive) out[(size_t)ge * OUTW + TMAIN + t] = yprev;
    }
}

extern "C" void kernel_launch(void* const* d_in, const int* in_sizes, int n_in,
                              void* d_out, int out_size, void* d_ws, size_t ws_size,
                              hipStream_t stream) {
    const float* x    = (const float*)d_in[0];
    const float* Wih1 = (const float*)d_in[1];
    const float* Whh1 = (const float*)d_in[2];
    const float* bih1 = (const float*)d_in[3];
    const float* bhh1 = (const float*)d_in[4];
    const float* Wih2 = (const float*)d_in[5];
    const float* Whh2 = (const float*)d_in[6];
    const float* bih2 = (const float*)d_in[7];
    const float* bhh2 = (const float*)d_in[8];
    const float* Wlin = (const float*)d_in[9];
    const float* blin = (const float*)d_in[10];
    const int*   futp = (const int*)d_in[11];
    float* out = (float*)d_out;

    int grid = (NB + EPB - 1) / EPB; // 342 single-wave blocks
    lstm2_kernel<<<grid, 64, 0, stream>>>(x, Wih1, Whh1, bih1, bhh1,
                                          Wih2, Whh2, bih2, bhh2,
                                          Wlin, blin, futp, out);
}

// Round 3
// 516.978 us; speedup vs baseline: 1.3998x; 1.1711x over previous
//
#include <hip/hip_runtime.h>

// 2-layer LSTM (HID=10), B=2048, T=1024 main + F=64 future steps.
// Round 3 decomposition: ONE element per wave/block, 40 active lanes.
// Lane L = k*10+u owns gate row L (k in {i,f,g,o}, u = hidden unit):
//   - per-lane weights ~43 floats (whh1 row 10, wih2 row 10, whh2 row 10,
//     wih1 1, combined biases 2, wlin 10) -> fully register-resident.
//   - 2048 blocks -> 8 blocks/CU -> 2 waves/SIMD on ALL 1024 SIMDs.
//   - uniform activation: sigma/tanh both = A + B*rcp(1 + exp2(K*x)) with
//     per-lane constants -> one act sequence covers all 4 gates (2 trans).
//   - cell update redundant on the 4 gate-lanes of a unit (4 bperm), h
//     broadcast to all lanes (10 bperm). No LDS; x read wave-uniform from
//     global with one-group-ahead float4 prefetch.

#define NB 2048
#define TMAIN 1024
#define HID 10

#define PIN(v) asm volatile("" : "+v"(v))

__global__ __launch_bounds__(64, 2) void lstm2_kernel(
    const float* __restrict__ x,
    const float* __restrict__ Wih1, const float* __restrict__ Whh1,
    const float* __restrict__ bih1, const float* __restrict__ bhh1,
    const float* __restrict__ Wih2, const float* __restrict__ Whh2,
    const float* __restrict__ bih2, const float* __restrict__ bhh2,
    const float* __restrict__ Wlin, const float* __restrict__ blin,
    const int* __restrict__ futp,
    float* __restrict__ out)
{
    const int lane = threadIdx.x;
    const int ge   = blockIdx.x;          // one batch element per block
    const int F    = futp[0];
    const int OUTW = TMAIN + F;

    const int L = (lane < 40) ? lane : 0; // lanes 40..63 shadow lane 0 (no stores)
    const int k = L / HID;                // gate: 0=i 1=f 2=g 3=o
    const int u = L - k * HID;            // hidden unit

    // ---- per-lane weights (row L) ----
    float whh1v[HID], wih2v[HID], whh2v[HID], wlinv[HID];
    #pragma unroll
    for (int j = 0; j < HID; ++j) {
        whh1v[j] = Whh1[L * HID + j];
        wih2v[j] = Wih2[L * HID + j];
        whh2v[j] = Whh2[L * HID + j];
        wlinv[j] = Wlin[j];
    }
    float wih1v = Wih1[L];                // W_ih1 is [40,1]
    float b1 = bih1[L] + bhh1[L];
    float b2 = bih2[L] + bhh2[L];
    float bl = blin[0];

    #pragma unroll
    for (int j = 0; j < HID; ++j) { PIN(whh1v[j]); PIN(wih2v[j]); PIN(whh2v[j]); PIN(wlinv[j]); }
    PIN(wih1v); PIN(b1); PIN(b2); PIN(bl);

    // ---- uniform activation constants (tanh for gate g, sigmoid otherwise) ----
    const bool isg = (k == 2);
    const float aK = isg ?  2.8853900817779268f : -1.4426950408889634f;
    const float aA = isg ?  1.0f : 0.0f;
    const float aB = isg ? -2.0f : 1.0f;
    // tanh constants (for cell state)
    const float tK = 2.8853900817779268f, tA = 1.0f, tB = -2.0f;

    // bperm byte addresses: the 4 gate-lanes of my unit, and the h-broadcast lanes
    const int adr_i = (0 * HID + u) * 4;
    const int adr_f = (1 * HID + u) * 4;
    const int adr_g = (2 * HID + u) * 4;
    const int adr_o = (3 * HID + u) * 4;

    // ---- state ----
    float c1 = 0.f, c2 = 0.f;
    float h1b[HID], h2b[HID];
    #pragma unroll
    for (int j = 0; j < HID; ++j) { h1b[j] = 0.f; h2b[j] = 0.f; }

    auto bp = [](int addr, float v) -> float {
        return __int_as_float(__builtin_amdgcn_ds_bpermute(addr, __float_as_int(v)));
    };

    auto step = [&](float xt) -> float {
        // ---- cell 1: my gate row ----
        float a = fmaf(xt, wih1v, b1);
        #pragma unroll
        for (int j = 0; j < HID; ++j) a = fmaf(h1b[j], whh1v[j], a);
        float act = fmaf(aB, __builtin_amdgcn_rcpf(1.0f + __builtin_amdgcn_exp2f(aK * a)), aA);
        // gather the 4 acts of my unit; redundant cell update on all 4 lanes
        float gi = bp(adr_i, act), gf = bp(adr_f, act), gg = bp(adr_g, act), go = bp(adr_o, act);
        c1 = fmaf(gf, c1, gi * gg);
        float tc = fmaf(tB, __builtin_amdgcn_rcpf(1.0f + __builtin_amdgcn_exp2f(tK * c1)), tA);
        float h1u = go * tc;
        #pragma unroll
        for (int j = 0; j < HID; ++j) h1b[j] = bp(j * 4, h1u); // lanes 0..9 hold h1_0..h1_9

        // ---- cell 2: my gate row ----
        float a2 = b2;
        #pragma unroll
        for (int j = 0; j < HID; ++j) a2 = fmaf(h1b[j], wih2v[j], a2);
        #pragma unroll
        for (int j = 0; j < HID; ++j) a2 = fmaf(h2b[j], whh2v[j], a2);
        float act2 = fmaf(aB, __builtin_amdgcn_rcpf(1.0f + __builtin_amdgcn_exp2f(aK * a2)), aA);
        float qi = bp(adr_i, act2), qf = bp(adr_f, act2), qg = bp(adr_g, act2), qo = bp(adr_o, act2);
        c2 = fmaf(qf, c2, qi * qg);
        float tc2 = fmaf(tB, __builtin_amdgcn_rcpf(1.0f + __builtin_amdgcn_exp2f(tK * c2)), tA);
        float h2u = qo * tc2;
        #pragma unroll
        for (int j = 0; j < HID; ++j) h2b[j] = bp(j * 4, h2u);

        // ---- linear head (redundant on all lanes; feeds future loop for free) ----
        float y = bl;
        #pragma unroll
        for (int j = 0; j < HID; ++j) y = fmaf(h2b[j], wlinv[j], y);
        return y;
    };

    // ---- main loop: 4 steps/group, x prefetched one group ahead ----
    const float4* xrow = (const float4*)(x + (size_t)ge * TMAIN);
    float4* orow = (float4*)(out + (size_t)ge * OUTW);  // OUTW=1088 -> 16B-aligned rows
    float4 xv = xrow[0];
    float yprev = 0.f;
    #pragma unroll 1
    for (int t4 = 0; t4 < TMAIN / 4; ++t4) {
        float4 xn = (t4 + 1 < TMAIN / 4) ? xrow[t4 + 1] : make_float4(0.f, 0.f, 0.f, 0.f);
        float4 yv;
        yv.x = step(xv.x);
        yv.y = step(xv.y);
        yv.z = step(xv.z);
        yv.w = step(xv.w);
        if (lane == 0) orow[t4] = yv;
        yprev = yv.w;
        xv = xn;
    }

    // ---- future loop: y feeds back (every lane already has y) ----
    int t = 0;
    #pragma unroll 1
    for (; t + 3 < F; t += 4) {
        float4 yv;
        yv.x = step(yprev);
        yv.y = step(yv.x);
        yv.z = step(yv.y);
        yv.w = step(yv.z);
        if (lane == 0) orow[(TMAIN + t) / 4] = yv;
        yprev = yv.w;
    }
    #pragma unroll 1
    for (; t < F; ++t) {
        yprev = step(yprev);
        if (lane == 0) out[(size_t)ge * OUTW + TMAIN + t] = yprev;
    }
}

extern "C" void kernel_launch(void* const* d_in, const int* in_sizes, int n_in,
                              void* d_out, int out_size, void* d_ws, size_t ws_size,
                              hipStream_t stream) {
    const float* x    = (const float*)d_in[0];
    const float* Wih1 = (const float*)d_in[1];
    const float* Whh1 = (const float*)d_in[2];
    const float* bih1 = (const float*)d_in[3];
    const float* bhh1 = (const float*)d_in[4];
    const float* Wih2 = (const float*)d_in[5];
    const float* Whh2 = (const float*)d_in[6];
    const float* bih2 = (const float*)d_in[7];
    const float* bhh2 = (const float*)d_in[8];
    const float* Wlin = (const float*)d_in[9];
    const float* blin = (const float*)d_in[10];
    const int*   futp = (const int*)d_in[11];
    float* out = (float*)d_out;

    lstm2_kernel<<<NB, 64, 0, stream>>>(x, Wih1, Whh1, bih1, bhh1,
                                        Wih2, Whh2, bih2, bhh2,
                                        Wlin, blin, futp, out);
}